// Round 4
// baseline (697.899 us; speedup 1.0000x reference)
//
#include <hip/hip_runtime.h>

#define N_NODES 50000
#define N_EDGES 1600000
#define R_WAV 4
#define D 128
#define NB 391                 // ceil(50000/128) buckets of 128 rows
#define CHUNK 4096             // edges per hist/partition block
#define NPBLK ((N_EDGES + CHUNK - 1) / CHUNK)   // 391
#define MAXB 4800              // bucket capacity for LDS sort (mean 4092, sigma 64)
#define RP_STRIDE 50016        // ints per row_ptr array (>= N+1), batched layout

typedef unsigned int u32;
typedef unsigned short u16;

// fp32 -> bf16 bits, round-to-nearest-even
static __device__ inline u16 f2bf(float f) {
    u32 u = __float_as_uint(f);
    u = (u + 0x7FFFu + ((u >> 16) & 1u)) >> 16;
    return (u16)u;
}
static __device__ inline float bf_lo(u32 u) { return __uint_as_float(u << 16); }
static __device__ inline float bf_hi(u32 u) { return __uint_as_float(u & 0xFFFF0000u); }

// packed bf16 pair -> two fp32 FMAs into a float2 accumulator (pairs adjacent
// so the compiler can form v_pk_fma_f32)
static __device__ inline void fma2(float2& acc, float v, u32 packed) {
    acc.x += v * bf_lo(packed);
    acc.y += v * bf_hi(packed);
}

// ---------------- GEMM: h = x @ W, bf16 row-major [N][128] -------------------
__global__ __launch_bounds__(128) void gemm_xw(const float* __restrict__ x,
                                               const float* __restrict__ W,
                                               u16* __restrict__ h) {
    const int j = threadIdx.x;
    const int row0 = blockIdx.x * 16;
    const float* xr = x + (size_t)row0 * D;
    float acc[16];
#pragma unroll
    for (int r = 0; r < 16; ++r) acc[r] = 0.f;
#pragma unroll 4
    for (int k = 0; k < 128; ++k) {
        const float w = W[k * D + j];
#pragma unroll
        for (int r = 0; r < 16; ++r) acc[r] += xr[r * D + k] * w;
    }
#pragma unroll
    for (int r = 0; r < 16; ++r) h[(size_t)(row0 + r) * D + j] = f2bf(acc[r]);
}

// ------ hist: per-chunk bucket histogram (saved for partition+scan) ----------
__global__ __launch_bounds__(256) void bucket_hist_all(const int* __restrict__ rows_all,
                                                       int* __restrict__ hist) {
    __shared__ int lh[NB];
    const int r = blockIdx.y;
    const int* rows = rows_all + (size_t)r * N_EDGES;
    const int tid = threadIdx.x;
    for (int i = tid; i < NB; i += 256) lh[i] = 0;
    __syncthreads();
    const int e0 = blockIdx.x * CHUNK;
    const int e1 = min(e0 + CHUNK, N_EDGES);
    for (int i = e0 + tid; i < e1; i += 256) atomicAdd(&lh[rows[i] >> 7], 1);
    __syncthreads();
    int* hc = hist + ((size_t)r * NPBLK + blockIdx.x) * NB;
    for (int i = tid; i < NB; i += 256) hc[i] = lh[i];
}

// ------ chunk_scan: per-bucket exclusive prefix over chunks + totals ---------
__global__ __launch_bounds__(512) void chunk_scan(const int* __restrict__ hist,
                                                  int* __restrict__ chunkpre,
                                                  int* __restrict__ cnt) {
    __shared__ int sa[512], sb[512];
    const int b = blockIdx.x;
    const int r = blockIdx.y;
    const int tid = threadIdx.x;
    const int v = (tid < NPBLK) ? hist[((size_t)r * NPBLK + tid) * NB + b] : 0;
    sa[tid] = v;
    int* cur = sa;
    int* nxt = sb;
    for (int d = 1; d < 512; d <<= 1) {
        __syncthreads();
        int t = cur[tid];
        if (tid >= d) t += cur[tid - d];
        nxt[tid] = t;
        int* tmp = cur; cur = nxt; nxt = tmp;
    }
    __syncthreads();
    const int excl = cur[tid] - v;
    if (tid < NPBLK) chunkpre[((size_t)r * NPBLK + tid) * NB + b] = excl;
    if (tid == NPBLK - 1) cnt[r * NB + b] = excl + v;
}

// ------------- batched scan of bucket counts: grid R_WAV ---------------------
__global__ __launch_bounds__(512) void scan_buckets_all(const int* __restrict__ cnt4,
                                                        int* __restrict__ bptr4) {
    __shared__ int sa[512], sb[512];
    const int r = blockIdx.x;
    const int* cnt = cnt4 + r * NB;
    int* bptr = bptr4 + r * (NB + 1);
    const int tid = threadIdx.x;
    const int v = (tid < NB) ? cnt[tid] : 0;
    sa[tid] = v;
    int* cur = sa;
    int* nxt = sb;
    for (int d = 1; d < 512; d <<= 1) {
        __syncthreads();
        int t = cur[tid];
        if (tid >= d) t += cur[tid - d];
        nxt[tid] = t;
        int* tmp = cur; cur = nxt; nxt = tmp;
    }
    __syncthreads();
    const int excl = cur[tid] - v;
    if (tid <= NB) bptr[tid] = excl;
}

// ---------------- partition: single edge pass, deterministic bases -----------
__global__ __launch_bounds__(256) void partition_kernel(const int* __restrict__ rows,
                                                        const int* __restrict__ cols,
                                                        const float* __restrict__ vals,
                                                        const int* __restrict__ bptr_all,
                                                        const int* __restrict__ chunkpre,
                                                        const int* __restrict__ hist,
                                                        u32* __restrict__ cvA,
                                                        u16* __restrict__ rowloc) {
    const int r = blockIdx.y;
    rows   += (size_t)r * N_EDGES;
    cols   += (size_t)r * N_EDGES;
    vals   += (size_t)r * N_EDGES;
    cvA    += (size_t)r * N_EDGES;
    rowloc += (size_t)r * N_EDGES;
    const int* bptr = bptr_all + r * (NB + 1);
    const int* hc   = hist     + ((size_t)r * NPBLK + blockIdx.x) * NB;
    const int* cp   = chunkpre + ((size_t)r * NPBLK + blockIdx.x) * NB;
    __shared__ int lh[NB], lptr[NB], lcur[NB], lbase[NB];
    __shared__ int sa[256], sb[256];
    __shared__ u32 st_cv[CHUNK];
    __shared__ u16 st_rl[CHUNK];
    const int tid = threadIdx.x;
    for (int i = tid; i < NB; i += 256) lh[i] = hc[i];
    __syncthreads();
    const int e0 = blockIdx.x * CHUNK;
    const int e1 = min(e0 + CHUNK, N_EDGES);
    const int cnt = e1 - e0;
    const int p0 = (2 * tid < NB) ? lh[2 * tid] : 0;
    const int p1 = (2 * tid + 1 < NB) ? lh[2 * tid + 1] : 0;
    sa[tid] = p0 + p1;
    int* cur = sa;
    int* nxt = sb;
    for (int d = 1; d < 256; d <<= 1) {
        __syncthreads();
        int t = cur[tid];
        if (tid >= d) t += cur[tid - d];
        nxt[tid] = t;
        int* tmp = cur; cur = nxt; nxt = tmp;
    }
    __syncthreads();
    const int pe = cur[tid] - (p0 + p1);
    if (2 * tid < NB)     { lptr[2 * tid] = pe;           lcur[2 * tid] = pe; }
    if (2 * tid + 1 < NB) { lptr[2 * tid + 1] = pe + p0;  lcur[2 * tid + 1] = pe + p0; }
    __syncthreads();
    for (int i = e0 + tid; i < e1; i += 256) {
        const int row = rows[i];
        const int b = row >> 7;
        const int pos = atomicAdd(&lcur[b], 1);
        st_cv[pos] = ((u32)f2bf(vals[i]) << 16) | ((u32)cols[i] & 0xFFFFu);
        st_rl[pos] = (u16)row;
    }
    for (int b = tid; b < NB; b += 256) lbase[b] = bptr[b] + cp[b] - lptr[b];
    __syncthreads();
    for (int i = tid; i < cnt; i += 256) {
        const u16 rl = st_rl[i];
        const int b = (int)rl >> 7;
        const int o = lbase[b] + i;
        cvA[o] = st_cv[i];
        rowloc[o] = rl;
    }
}

// ------- per-bucket CSR: 128-bin counting sort of pre-packed 4B edges --------
__global__ __launch_bounds__(256) void bucket_csr(const int* __restrict__ bptr_all,
                                                  const u32* __restrict__ cvA,
                                                  const u16* __restrict__ rowloc,
                                                  u32* __restrict__ cv4,
                                                  int* __restrict__ row_ptr) {
    const int r = blockIdx.y;
    const int* bptr = bptr_all + r * (NB + 1);
    cvA     += (size_t)r * N_EDGES;
    rowloc  += (size_t)r * N_EDGES;
    cv4     += (size_t)r * N_EDGES;
    row_ptr += r * RP_STRIDE;
    __shared__ int lh[128], lexcl[128], lcur[128];
    __shared__ u32 st[MAXB];
    const int b = blockIdx.x;
    const int s = bptr[b], e1 = bptr[b + 1];
    const int cnt = e1 - s;
    const int tid = threadIdx.x;
    if (tid < 128) lh[tid] = 0;
    __syncthreads();
    for (int i = s + tid; i < e1; i += 256)
        atomicAdd(&lh[(int)rowloc[i] & 127], 1);
    __syncthreads();
    if (tid < 64) {
        const int p0 = lh[2 * tid], p1 = lh[2 * tid + 1];
        int ssum = p0 + p1;
#pragma unroll
        for (int d = 1; d < 64; d <<= 1) {
            const int t = __shfl_up(ssum, d, 64);
            if (tid >= d) ssum += t;
        }
        const int pe = ssum - (p0 + p1);
        lexcl[2 * tid] = pe;          lcur[2 * tid] = pe;
        lexcl[2 * tid + 1] = pe + p0; lcur[2 * tid + 1] = pe + p0;
    }
    __syncthreads();
    for (int i = s + tid; i < e1; i += 256) {
        const int lr = (int)rowloc[i] & 127;
        const int pos = atomicAdd(&lcur[lr], 1);
        if (pos < MAXB) st[pos] = cvA[i];
    }
    __syncthreads();
    const int wb = (cnt < MAXB) ? cnt : MAXB;
    for (int i = tid; i < wb; i += 256) cv4[s + i] = st[i];
    if (tid < 128) {
        const int row = (b << 7) + tid;
        if (row < N_NODES) row_ptr[row] = s + lexcl[tid];
    }
    if (blockIdx.x == 0 && tid == 0) row_ptr[N_NODES] = N_EDGES;
}

// ---------------- SpMM pass 1: y = bf16( filt * (A @ h) ) --------------------
// One wave per row; batched over r (h shared across r). Quarter structure:
// 16 lanes per edge, dwordx4 gathers (4 edges per gather instruction), lane
// owns 8 channels [8*l4, 8*l4+8). Halves gather-instr + address VALU vs the
// uint2/half scheme.
__global__ __launch_bounds__(256) void spmm1(const int* __restrict__ row_ptr,
                                             const u32* __restrict__ cvp,
                                             const u32* __restrict__ h2,
                                             const float* __restrict__ filt,
                                             u32* __restrict__ y2) {
    const int r = blockIdx.y;
    row_ptr += r * RP_STRIDE;
    cvp     += (size_t)r * N_EDGES;
    filt    += (size_t)r * N_NODES;
    y2      += (size_t)r * (N_NODES * 64);
    const int row = __builtin_amdgcn_readfirstlane(blockIdx.x * 4 + (threadIdx.x >> 6));
    const int lane = threadIdx.x & 63;
    const int q  = (lane >> 4) & 3;   // quarter: which edge of the group of 4
    const int l4 = lane & 15;         // channel block within the edge
    int e = row_ptr[row];
    const int end = row_ptr[row + 1];
    float2 a0 = {0.f, 0.f}, a1 = {0.f, 0.f}, a2 = {0.f, 0.f}, a3 = {0.f, 0.f};
    float2 b0 = {0.f, 0.f}, b1 = {0.f, 0.f}, b2 = {0.f, 0.f}, b3 = {0.f, 0.f};
    for (; e + 16 <= end; e += 16) {
        const u32 c0 = cvp[e],      c1 = cvp[e + 1],  c2 = cvp[e + 2],  c3 = cvp[e + 3];
        const u32 c4 = cvp[e + 4],  c5 = cvp[e + 5],  c6 = cvp[e + 6],  c7 = cvp[e + 7];
        const u32 c8 = cvp[e + 8],  c9 = cvp[e + 9],  cA = cvp[e + 10], cB = cvp[e + 11];
        const u32 cC = cvp[e + 12], cD = cvp[e + 13], cE = cvp[e + 14], cF = cvp[e + 15];
        const u32 uA0 = (q & 2) ? ((q & 1) ? c3 : c2) : ((q & 1) ? c1 : c0);
        const u32 uB0 = (q & 2) ? ((q & 1) ? c7 : c6) : ((q & 1) ? c5 : c4);
        const u32 uA1 = (q & 2) ? ((q & 1) ? cB : cA) : ((q & 1) ? c9 : c8);
        const u32 uB1 = (q & 2) ? ((q & 1) ? cF : cE) : ((q & 1) ? cD : cC);
        const uint4 gA0 = *(const uint4*)(h2 + (uA0 & 0xFFFFu) * 64 + 4 * l4);
        const uint4 gB0 = *(const uint4*)(h2 + (uB0 & 0xFFFFu) * 64 + 4 * l4);
        const uint4 gA1 = *(const uint4*)(h2 + (uA1 & 0xFFFFu) * 64 + 4 * l4);
        const uint4 gB1 = *(const uint4*)(h2 + (uB1 & 0xFFFFu) * 64 + 4 * l4);
        const float vA0 = __uint_as_float(uA0 & 0xFFFF0000u);
        const float vB0 = __uint_as_float(uB0 & 0xFFFF0000u);
        const float vA1 = __uint_as_float(uA1 & 0xFFFF0000u);
        const float vB1 = __uint_as_float(uB1 & 0xFFFF0000u);
        fma2(a0, vA0, gA0.x); fma2(a1, vA0, gA0.y); fma2(a2, vA0, gA0.z); fma2(a3, vA0, gA0.w);
        fma2(b0, vB0, gB0.x); fma2(b1, vB0, gB0.y); fma2(b2, vB0, gB0.z); fma2(b3, vB0, gB0.w);
        fma2(a0, vA1, gA1.x); fma2(a1, vA1, gA1.y); fma2(a2, vA1, gA1.z); fma2(a3, vA1, gA1.w);
        fma2(b0, vB1, gB1.x); fma2(b1, vB1, gB1.y); fma2(b2, vB1, gB1.z); fma2(b3, vB1, gB1.w);
    }
    for (; e + 8 <= end; e += 8) {
        const u32 c0 = cvp[e],     c1 = cvp[e + 1], c2 = cvp[e + 2], c3 = cvp[e + 3];
        const u32 c4 = cvp[e + 4], c5 = cvp[e + 5], c6 = cvp[e + 6], c7 = cvp[e + 7];
        const u32 uA = (q & 2) ? ((q & 1) ? c3 : c2) : ((q & 1) ? c1 : c0);
        const u32 uB = (q & 2) ? ((q & 1) ? c7 : c6) : ((q & 1) ? c5 : c4);
        const uint4 gA = *(const uint4*)(h2 + (uA & 0xFFFFu) * 64 + 4 * l4);
        const uint4 gB = *(const uint4*)(h2 + (uB & 0xFFFFu) * 64 + 4 * l4);
        const float vA = __uint_as_float(uA & 0xFFFF0000u);
        const float vB = __uint_as_float(uB & 0xFFFF0000u);
        fma2(a0, vA, gA.x); fma2(a1, vA, gA.y); fma2(a2, vA, gA.z); fma2(a3, vA, gA.w);
        fma2(b0, vB, gB.x); fma2(b1, vB, gB.y); fma2(b2, vB, gB.z); fma2(b3, vB, gB.w);
    }
    for (; e < end; e += 4) {
        const u32 u = (e + q < end) ? cvp[e + q] : 0u;
        const uint4 g = *(const uint4*)(h2 + (u & 0xFFFFu) * 64 + 4 * l4);
        const float v = __uint_as_float(u & 0xFFFF0000u);
        fma2(a0, v, g.x); fma2(a1, v, g.y); fma2(a2, v, g.z); fma2(a3, v, g.w);
    }
    a0.x += b0.x; a0.y += b0.y; a1.x += b1.x; a1.y += b1.y;
    a2.x += b2.x; a2.y += b2.y; a3.x += b3.x; a3.y += b3.y;
    float s[8] = {a0.x, a0.y, a1.x, a1.y, a2.x, a2.y, a3.x, a3.y};
#pragma unroll
    for (int i = 0; i < 8; ++i) {
        s[i] += __shfl_xor(s[i], 16, 64);
        s[i] += __shfl_xor(s[i], 32, 64);
    }
    const float f = filt[row];
    if (lane < 16) {
        uint4 o;
        o.x = (u32)f2bf(f * s[0]) | ((u32)f2bf(f * s[1]) << 16);
        o.y = (u32)f2bf(f * s[2]) | ((u32)f2bf(f * s[3]) << 16);
        o.z = (u32)f2bf(f * s[4]) | ((u32)f2bf(f * s[5]) << 16);
        o.w = (u32)f2bf(f * s[6]) | ((u32)f2bf(f * s[7]) << 16);
        *(uint4*)(y2 + (size_t)row * 64 + 4 * l4) = o;
    }
}

// ---------------- SpMM pass 2 (per-r; best measured L2 locality) -------------
template <bool FIRST>
__global__ __launch_bounds__(256) void spmm2(const int* __restrict__ row_ptr,
                                             const u32* __restrict__ cvp,
                                             const u32* __restrict__ y2,
                                             const float* __restrict__ bias,
                                             float* __restrict__ out) {
    const int row = __builtin_amdgcn_readfirstlane(blockIdx.x * 4 + (threadIdx.x >> 6));
    const int lane = threadIdx.x & 63;
    const int q  = (lane >> 4) & 3;
    const int l4 = lane & 15;
    int e = row_ptr[row];
    const int end = row_ptr[row + 1];
    float2 a0 = {0.f, 0.f}, a1 = {0.f, 0.f}, a2 = {0.f, 0.f}, a3 = {0.f, 0.f};
    float2 b0 = {0.f, 0.f}, b1 = {0.f, 0.f}, b2 = {0.f, 0.f}, b3 = {0.f, 0.f};
    for (; e + 16 <= end; e += 16) {
        const u32 c0 = cvp[e],      c1 = cvp[e + 1],  c2 = cvp[e + 2],  c3 = cvp[e + 3];
        const u32 c4 = cvp[e + 4],  c5 = cvp[e + 5],  c6 = cvp[e + 6],  c7 = cvp[e + 7];
        const u32 c8 = cvp[e + 8],  c9 = cvp[e + 9],  cA = cvp[e + 10], cB = cvp[e + 11];
        const u32 cC = cvp[e + 12], cD = cvp[e + 13], cE = cvp[e + 14], cF = cvp[e + 15];
        const u32 uA0 = (q & 2) ? ((q & 1) ? c3 : c2) : ((q & 1) ? c1 : c0);
        const u32 uB0 = (q & 2) ? ((q & 1) ? c7 : c6) : ((q & 1) ? c5 : c4);
        const u32 uA1 = (q & 2) ? ((q & 1) ? cB : cA) : ((q & 1) ? c9 : c8);
        const u32 uB1 = (q & 2) ? ((q & 1) ? cF : cE) : ((q & 1) ? cD : cC);
        const uint4 gA0 = *(const uint4*)(y2 + (uA0 & 0xFFFFu) * 64 + 4 * l4);
        const uint4 gB0 = *(const uint4*)(y2 + (uB0 & 0xFFFFu) * 64 + 4 * l4);
        const uint4 gA1 = *(const uint4*)(y2 + (uA1 & 0xFFFFu) * 64 + 4 * l4);
        const uint4 gB1 = *(const uint4*)(y2 + (uB1 & 0xFFFFu) * 64 + 4 * l4);
        const float vA0 = __uint_as_float(uA0 & 0xFFFF0000u);
        const float vB0 = __uint_as_float(uB0 & 0xFFFF0000u);
        const float vA1 = __uint_as_float(uA1 & 0xFFFF0000u);
        const float vB1 = __uint_as_float(uB1 & 0xFFFF0000u);
        fma2(a0, vA0, gA0.x); fma2(a1, vA0, gA0.y); fma2(a2, vA0, gA0.z); fma2(a3, vA0, gA0.w);
        fma2(b0, vB0, gB0.x); fma2(b1, vB0, gB0.y); fma2(b2, vB0, gB0.z); fma2(b3, vB0, gB0.w);
        fma2(a0, vA1, gA1.x); fma2(a1, vA1, gA1.y); fma2(a2, vA1, gA1.z); fma2(a3, vA1, gA1.w);
        fma2(b0, vB1, gB1.x); fma2(b1, vB1, gB1.y); fma2(b2, vB1, gB1.z); fma2(b3, vB1, gB1.w);
    }
    for (; e + 8 <= end; e += 8) {
        const u32 c0 = cvp[e],     c1 = cvp[e + 1], c2 = cvp[e + 2], c3 = cvp[e + 3];
        const u32 c4 = cvp[e + 4], c5 = cvp[e + 5], c6 = cvp[e + 6], c7 = cvp[e + 7];
        const u32 uA = (q & 2) ? ((q & 1) ? c3 : c2) : ((q & 1) ? c1 : c0);
        const u32 uB = (q & 2) ? ((q & 1) ? c7 : c6) : ((q & 1) ? c5 : c4);
        const uint4 gA = *(const uint4*)(y2 + (uA & 0xFFFFu) * 64 + 4 * l4);
        const uint4 gB = *(const uint4*)(y2 + (uB & 0xFFFFu) * 64 + 4 * l4);
        const float vA = __uint_as_float(uA & 0xFFFF0000u);
        const float vB = __uint_as_float(uB & 0xFFFF0000u);
        fma2(a0, vA, gA.x); fma2(a1, vA, gA.y); fma2(a2, vA, gA.z); fma2(a3, vA, gA.w);
        fma2(b0, vB, gB.x); fma2(b1, vB, gB.y); fma2(b2, vB, gB.z); fma2(b3, vB, gB.w);
    }
    for (; e < end; e += 4) {
        const u32 u = (e + q < end) ? cvp[e + q] : 0u;
        const uint4 g = *(const uint4*)(y2 + (u & 0xFFFFu) * 64 + 4 * l4);
        const float v = __uint_as_float(u & 0xFFFF0000u);
        fma2(a0, v, g.x); fma2(a1, v, g.y); fma2(a2, v, g.z); fma2(a3, v, g.w);
    }
    a0.x += b0.x; a0.y += b0.y; a1.x += b1.x; a1.y += b1.y;
    a2.x += b2.x; a2.y += b2.y; a3.x += b3.x; a3.y += b3.y;
    float s[8] = {a0.x, a0.y, a1.x, a1.y, a2.x, a2.y, a3.x, a3.y};
#pragma unroll
    for (int i = 0; i < 8; ++i) {
        s[i] += __shfl_xor(s[i], 16, 64);
        s[i] += __shfl_xor(s[i], 32, 64);
    }
    if (lane < 16) {
        float* op = out + (size_t)row * D + 8 * l4;
        if (FIRST) {
            const float4 bb0 = *(const float4*)(bias + 8 * l4);
            const float4 bb1 = *(const float4*)(bias + 8 * l4 + 4);
            *(float4*)op       = make_float4(s[0] + bb0.x, s[1] + bb0.y, s[2] + bb0.z, s[3] + bb0.w);
            *(float4*)(op + 4) = make_float4(s[4] + bb1.x, s[5] + bb1.y, s[6] + bb1.z, s[7] + bb1.w);
        } else {
            const float4 cc0 = *(const float4*)op;
            const float4 cc1 = *(const float4*)(op + 4);
            *(float4*)op       = make_float4(cc0.x + s[0], cc0.y + s[1], cc0.z + s[2], cc0.w + s[3]);
            *(float4*)(op + 4) = make_float4(cc1.x + s[4], cc1.y + s[5], cc1.z + s[6], cc1.w + s[7]);
        }
    }
}

extern "C" void kernel_launch(void* const* d_in, const int* in_sizes, int n_in,
                              void* d_out, int out_size, void* d_ws, size_t ws_size,
                              hipStream_t stream) {
    const float* x    = (const float*)d_in[0];  // [N,128]
    const float* vals = (const float*)d_in[1];  // [R,E]
    const float* W    = (const float*)d_in[2];  // [128,128]
    const float* filt = (const float*)d_in[3];  // [R*N,1]
    const float* bias = (const float*)d_in[4];  // [128]
    const int*   rows = (const int*)d_in[5];    // [R,E]
    const int*   cols = (const int*)d_in[6];    // [R,E]
    float* out = (float*)d_out;                 // [N,128]

    char* ws = (char*)d_ws;
    // Layout (<= 90,419,968 B, proven available):
    //   [0, 12.8M)        h bf16 [N][128]
    //   [12.8M, 64M)      region B:
    //                       cvA  u32 [R][E]  @ 12.8M   (25.6 MB)
    //                       rowloc u16 [R][E] @ 38.4M  (12.8 MB)
    //                     aliased by y2 bf16 [R][N][128] @ 12.8M (51.2 MB)
    //                     (cvA/rowloc dead before spmm1 writes y2)
    //   [64M, 89.6M)      cv4 u32 [R][E]  (alias: hist+cpre, 4.9 MB, dead
    //                     before bucket_csr writes cv4)
    //   [89.6M, ...)      rp, cnt, bptr
    u16*  h      = (u16*)(ws);
    u32*  cvA    = (u32*)(ws + 12800000);
    u16*  rowloc = (u16*)(ws + 38400000);
    u32*  y2     = (u32*)(ws + 12800000);          // alias of cvA/rowloc
    u32*  cv4    = (u32*)(ws + 64000000);
    int*  hist   = (int*)(ws + 64000000);          // alias of cv4 region
    int*  cpre   = (int*)(ws + 66446096);          // alias of cv4 region
    int*  rp     = (int*)(ws + 89600000);          // 4 x RP_STRIDE ints
    int*  cnt4   = (int*)(ws + 90400512);          // 4*NB ints
    int*  bptr4  = (int*)(ws + 90406768);          // 4*(NB+1) ints

    bucket_hist_all<<<dim3(NPBLK, R_WAV), 256, 0, stream>>>(rows, hist);
    chunk_scan<<<dim3(NB, R_WAV), 512, 0, stream>>>(hist, cpre, cnt4);
    scan_buckets_all<<<R_WAV, 512, 0, stream>>>(cnt4, bptr4);
    partition_kernel<<<dim3(NPBLK, R_WAV), 256, 0, stream>>>(rows, cols, vals,
                                                             bptr4, cpre, hist,
                                                             cvA, rowloc);
    bucket_csr<<<dim3(NB, R_WAV), 256, 0, stream>>>(bptr4, cvA, rowloc, cv4, rp);

    gemm_xw<<<N_NODES / 16, 128, 0, stream>>>(x, W, h);

    spmm1<<<dim3(N_NODES / 4, R_WAV), 256, 0, stream>>>(rp, cv4, (const u32*)h,
                                                        filt, y2);
    for (int r = 0; r < R_WAV; ++r) {
        const int* rp_r  = rp + r * RP_STRIDE;
        const u32* cv4_r = cv4 + (size_t)r * N_EDGES;
        const u32* y2_r  = y2 + (size_t)r * (N_NODES * 64);
        if (r == 0)
            spmm2<true><<<N_NODES / 4, 256, 0, stream>>>(rp_r, cv4_r, y2_r, bias, out);
        else
            spmm2<false><<<N_NODES / 4, 256, 0, stream>>>(rp_r, cv4_r, y2_r, bias, out);
    }
}